// Round 12
// baseline (179.016 us; speedup 1.0000x reference)
//
#include <hip/hip_runtime.h>
#include <stdint.h>

#define N_NODES 50000
#define N_EDGES 800000
#define H_DIM 128
#define N_REL 40
#define N_BASES 4
#define N_RANGES 196         // node ranges of 256 (dst >> 8)
#define EP_BLOCKS 400        // edge chunks of 2000
#define EDGES_PER_BLK 2000
#define STAGE_CAP 5120       // LDS staging capacity for bucket_sort
#define CAST_BLOCKS 1563     // ceil(800000/512)
#define NTILES 1563          // ceil(50000/32)
#define AGG_GRID 1024        // exactly 4 blocks/CU; block b does tiles {b, b+1024}

typedef __attribute__((ext_vector_type(8))) short bf16x8;
typedef __attribute__((ext_vector_type(4))) float f32x4;

// round-to-nearest-even f32 -> bf16 bits
__device__ __forceinline__ unsigned short f2bf(float f) {
    unsigned int u = __float_as_uint(f);
    unsigned int r = u + 0x7fffu + ((u >> 16) & 1u);
    return (unsigned short)(r >> 16);
}

// ---------------------------------------------------------------------------
// K0: edge_pack (400 blocks x 1024, 2000 edges each — 2 iterations/block).
// Pack edges + per-(chunk,bucket) LDS histogram -> gcnt[chunk][range].
// Block 0 zeroes the 16-entry over-read pad. LDS atomics only.
// pkd[e] = { src | etype<<20 , dst | nbf<<17 }  (nbf = bf16 of norm >= 0)
__global__ __launch_bounds__(1024) void edge_pack(
        const int* __restrict__ src, const int* __restrict__ dst,
        const int* __restrict__ etype, const float* __restrict__ norm,
        uint2* __restrict__ pkd, int* __restrict__ gcnt,
        unsigned* __restrict__ sorted_src, float4* __restrict__ sorted_cf) {
    __shared__ int lhist[N_RANGES];
    int blk = blockIdx.x;                   // 0..399
    int t = threadIdx.x;
    if (t < N_RANGES) lhist[t] = 0;
    if (blk == 0 && t >= 1008) {            // zero over-read pad
        int k = t - 1008;                   // 0..15
        sorted_src[N_EDGES + k] = 0u;
        sorted_cf[N_EDGES + k] = make_float4(0.f, 0.f, 0.f, 0.f);
    }
    __syncthreads();
    int e0 = blk * EDGES_PER_BLK;
    for (int i = t; i < EDGES_PER_BLK; i += 1024) {
        int e = e0 + i;
        int d = dst[e];
        unsigned int nbf = f2bf(norm[e]);   // <= 0x7FFF (norm >= 0)
        pkd[e] = make_uint2((unsigned)src[e] | ((unsigned)etype[e] << 20),
                            (unsigned)d | (nbf << 17));
        atomicAdd(&lhist[d >> 8], 1);
    }
    __syncthreads();
    if (t < N_RANGES) gcnt[blk * N_RANGES + t] = lhist[t];
}

// ---------------------------------------------------------------------------
// K1: bucket_scan_a (196 blocks x 512). Block r scans its bucket's 400
// chunk-counts -> RELATIVE blkbase[chunk][range] + bucket total btot[r].
__global__ __launch_bounds__(512) void bucket_scan_a(
        const int* __restrict__ gcnt, int* __restrict__ blkbase,
        int* __restrict__ btot) {
    __shared__ int wsum[8];
    int r = blockIdx.x;
    int t = threadIdx.x, lane = t & 63, w = t >> 6;
    int x = (t < EP_BLOCKS) ? gcnt[t * N_RANGES + r] : 0;
    int v = x;
#pragma unroll
    for (int d = 1; d < 64; d <<= 1) {
        int y = __shfl_up(v, d);
        if (lane >= d) v += y;
    }
    if (lane == 63) wsum[w] = v;
    __syncthreads();
    int wpre = 0;
#pragma unroll
    for (int ww = 0; ww < 7; ++ww)
        if (w > ww) wpre += wsum[ww];
    if (t < EP_BLOCKS) blkbase[t * N_RANGES + r] = wpre + v - x;
    if (t == 511) btot[r] = wpre + v;
}

// ---------------------------------------------------------------------------
// K2: stage2 (fused for overlap — scatter's low machine fill is covered by
// independent streaming blocks in the SAME dispatch):
//   blocks 0..399      : binscatter chunk b -> bucket-grouped order. Bases:
//                        196-wide shuffle scan of btot -> bstart; cursor =
//                        bstart + blkbase[b][range] (precomputed, coalesced).
//   blocks 400..1962   : cast h -> A bf16 (stride 128).
//   blocks 1963..1967  : repack basis_w/loop_w into frag-major wt3.
__global__ __launch_bounds__(512) void stage2(
        const float* __restrict__ h,
        const float* __restrict__ basis_w, const float* __restrict__ loop_w,
        const uint2* __restrict__ pkd, const int* __restrict__ blkbase,
        const int* __restrict__ btot,
        unsigned short* __restrict__ A, unsigned short* __restrict__ wt3,
        uint2* __restrict__ bucketed) {
    __shared__ int lcur[N_RANGES];
    __shared__ int wsum[8];
    int bid = blockIdx.x;
    int t = threadIdx.x;
    if (bid < EP_BLOCKS) {
        int lane = t & 63, w = t >> 6;
        int b = bid;
        int x = (t < N_RANGES) ? btot[t] : 0;
        int v = x;
#pragma unroll
        for (int d = 1; d < 64; d <<= 1) {
            int y = __shfl_up(v, d);
            if (lane >= d) v += y;
        }
        if (lane == 63) wsum[w] = v;
        __syncthreads();
        int wpre = 0;
#pragma unroll
        for (int ww = 0; ww < 7; ++ww)
            if (w > ww) wpre += wsum[ww];
        if (t < N_RANGES)
            lcur[t] = (wpre + v - x) + blkbase[b * N_RANGES + t];
        __syncthreads();
        int e0 = b * EDGES_PER_BLK;
        for (int i = t; i < EDGES_PER_BLK; i += 512) {
            uint2 p = pkd[e0 + i];
            int r = (p.y & 0x1FFFF) >> 8;
            int pos = atomicAdd(&lcur[r], 1);
            bucketed[pos] = p;
        }
    } else if (bid < EP_BLOCKS + CAST_BLOCKS) {
        int g = (bid - EP_BLOCKS) * 512 + t;    // [0, 800256)
        if (g < 800000) {
            int row = g >> 4;
            int cb = (g & 15) * 8;
            const float* p = h + (size_t)row * 128 + cb;
            float4 a0 = ((const float4*)p)[0];
            float4 a1 = ((const float4*)p)[1];
            bf16x8 o;
            o[0] = (short)f2bf(a0.x); o[1] = (short)f2bf(a0.y);
            o[2] = (short)f2bf(a0.z); o[3] = (short)f2bf(a0.w);
            o[4] = (short)f2bf(a1.x); o[5] = (short)f2bf(a1.y);
            o[6] = (short)f2bf(a1.z); o[7] = (short)f2bf(a1.w);
            *(bf16x8*)(A + (size_t)row * H_DIM + cb) = o;
        }
    } else {
        int mat = bid - EP_BLOCKS - CAST_BLOCKS;    // 0..3 basis, 4 loop
        const float* srcm = (mat < 4) ? (basis_w + mat * 16384) : loop_w;
        int koff = (mat < 4) ? (128 + mat * 128) : 0;
#pragma unroll
        for (int i = 0; i < 8; ++i) {
            int f = t + i * 512;                // [0,4096) float4 index
            int k = f >> 5;
            int j4 = (f & 31) * 4;
            float4 v = ((const float4*)srcm)[f];
            int kg = koff + k;
            int ks = kg >> 5;
            int quad = (kg >> 3) & 3;
            int jj = kg & 7;
            float vv[4] = {v.x, v.y, v.z, v.w};
#pragma unroll
            for (int d = 0; d < 4; ++d) {
                int j = j4 + d;
                int cg = j >> 4;
                int n16 = j & 15;
                wt3[(size_t)((ks * 8 + cg) * 64 + quad * 16 + n16) * 8 + jj] =
                    f2bf(vv[d]);
            }
        }
    }
}

// ---------------------------------------------------------------------------
// K3: bucket_sort (196 blocks x 1024 — round-10 version; the 4-way node
// split of round 11 regressed via 4x redundant histogram reads). One block
// per bucket; begin from a 196-wide scan of btot (precomputed).
// Pass 1: LDS per-dst histogram -> scan -> per-dst offsets (offs coalesced).
// Pass 2: place edges into LDS stage by exact sorted position, stream out
// coalesced as sorted_src (u32) + sorted_cf (float4 = w_comp[etype]*norm).
__global__ __launch_bounds__(1024) void bucket_sort(
        const int* __restrict__ btot, const uint2* __restrict__ bucketed,
        const float* __restrict__ w_comp,
        unsigned* __restrict__ sorted_src, float4* __restrict__ sorted_cf,
        int* __restrict__ offs) {
    __shared__ int hist[256];
    __shared__ int cur[256];
    __shared__ int wsum[16];
    __shared__ int sbeg;
    __shared__ uint2 stage[STAGE_CAP];
    int r = blockIdx.x;
    int t = threadIdx.x, lane = t & 63, w = t >> 6;
    int x = (t < N_RANGES) ? btot[t] : 0;
    int v = x;
#pragma unroll
    for (int d = 1; d < 64; d <<= 1) {
        int y = __shfl_up(v, d);
        if (lane >= d) v += y;
    }
    if (lane == 63) wsum[w] = v;
    if (t < 256) hist[t] = 0;
    __syncthreads();
    int wpre = 0;
#pragma unroll
    for (int ww = 0; ww < 15; ++ww)
        if (w > ww) wpre += wsum[ww];
    if (t == r) sbeg = wpre + v - x;
    __syncthreads();
    int begin = sbeg;
    int n = btot[r];
    int end = begin + n;
    for (int i = begin + t; i < end; i += 1024)
        atomicAdd(&hist[bucketed[i].y & 255], 1);
    __syncthreads();
    int x2 = (t < 256) ? hist[t] : 0;
    int v2 = x2;
#pragma unroll
    for (int d = 1; d < 64; d <<= 1) {
        int y = __shfl_up(v2, d);
        if (lane >= d) v2 += y;
    }
    if (lane == 63) wsum[w] = v2;
    __syncthreads();
    if (t < 256) {
        int wpre2 = 0;
#pragma unroll
        for (int ww = 0; ww < 3; ++ww)      // only waves 0..3 hold hist
            if (w > ww) wpre2 += wsum[ww];
        int excl_rel = wpre2 + v2 - x2;     // position within the region
        int node = r * 256 + t;
        if (node < N_NODES) offs[node] = begin + excl_rel;
        cur[t] = excl_rel;
    }
    if (r == N_RANGES - 1 && t == 0) offs[N_NODES] = N_EDGES;
    __syncthreads();
    if (n <= STAGE_CAP) {
        for (int i = begin + t; i < end; i += 1024) {
            uint2 p = bucketed[i];
            int pos = atomicAdd(&cur[p.y & 255], 1);
            stage[pos] = make_uint2(p.x, (p.y >> 17) << 16);
        }
        __syncthreads();
        for (int i = t; i < n; i += 1024) {
            uint2 p = stage[i];
            float nm = __uint_as_float(p.y);
            float4 wc = ((const float4*)w_comp)[p.x >> 20];
            sorted_src[begin + i] = p.x & 0xFFFFF;
            sorted_cf[begin + i] =
                make_float4(wc.x * nm, wc.y * nm, wc.z * nm, wc.w * nm);
        }
    } else {                                    // pathological fallback
        for (int i = begin + t; i < end; i += 1024) {
            uint2 p = bucketed[i];
            int pos = atomicAdd(&cur[p.y & 255], 1);
            float nm = __uint_as_float((p.y >> 17) << 16);
            float4 wc = ((const float4*)w_comp)[p.x >> 20];
            sorted_src[begin + pos] = p.x & 0xFFFFF;
            sorted_cf[begin + pos] =
                make_float4(wc.x * nm, wc.y * nm, wc.z * nm, wc.w * nm);
        }
    }
}

// ---------------------------------------------------------------------------
// K4 (fused aggregate + GEMM) — round-5/9/10 inner body verbatim, wrapped in
// a STATIC 2-tile loop: grid 1024 (exactly 4 blocks/CU), block b does tiles
// {b, b+1024} (second only if < 1563). Fixes the 1563/1024 = 1.53-wave grid
// quantization behind Occupancy~57% WITHOUT the round-3/4 spill machinery
// (no atomic counter, no LDS broadcast — tile index is a pure function of
// blockIdx; loop state is one SGPR). Falsifiable: VGPR must stay ~20-28 and
// WRITE_SIZE ~25MB, else this is the spill mode again and gets reverted.
// Phase 1: wave w aggregates nodes [tile*32 + 4w, +4); edge metadata from
// sorted_src/sorted_cf (wave-uniform -> s_load batches of 8); gathers are
// 256B bf16 rows, 8 outstanding; MASKED full batch for the remainder.
// Node's 512-wide f32 S -> bf16 -> LDS tile [32][640] (with own hbf row),
// rows XOR-swizzled (byte ^= (row&7)<<4) for bank-uniform ds_read_b128.
// Phase 2: 32x128x640 bf16 MFMA from LDS; wave = 16 cols; bias+relu.
__global__ __launch_bounds__(512, 8) void agg_gemm(
        const int* __restrict__ offs, const unsigned* __restrict__ ssrc,
        const float4* __restrict__ scf,
        const unsigned short* __restrict__ Ab,
        const unsigned short* __restrict__ wt3,
        const float* __restrict__ bias, float* __restrict__ out) {
    __shared__ __align__(16) unsigned short S[32 * 640];   // 40 KB
    int wv = threadIdx.x >> 6;
    int lane = threadIdx.x & 63;
    const unsigned int* Au = (const unsigned int*)Ab;
    int n16 = lane & 15;
    int quad = lane >> 4;
    const char* s0p = (const char*)S + n16 * 1280;
    const char* s1p = s0p + 16 * 1280;
    int swz2 = (n16 & 7) << 4;
    const unsigned short* bwp = wt3 + (size_t)wv * 512 + (size_t)lane * 8;

    for (int rep = 0; rep < 2; ++rep) {
        int tile = blockIdx.x + rep * AGG_GRID;
        if (tile >= NTILES) break;
        int nbase = tile * 32;

#pragma unroll
        for (int q = 0; q < 4; ++q) {
            int row = (wv << 2) + q;
            int v = __builtin_amdgcn_readfirstlane(nbase + row);
            float a0l = 0.f, a0h = 0.f, a1l = 0.f, a1h = 0.f;
            float a2l = 0.f, a2h = 0.f, a3l = 0.f, a3h = 0.f;
            unsigned int hb = 0u;
            if (v < N_NODES) {
                hb = Au[(size_t)v * 64 + lane];     // own hbf row
                int begin = __builtin_amdgcn_readfirstlane(offs[v]);
                int end   = __builtin_amdgcn_readfirstlane(offs[v + 1]);
                for (int j = begin; j < end; j += 8) {
                    int rem = end - j;              // uniform
                    unsigned su[8];
                    float4 c[8];
#pragma unroll
                    for (int k = 0; k < 8; ++k) su[k] = ssrc[j + k];
#pragma unroll
                    for (int k = 0; k < 8; ++k) c[k] = scf[j + k];
                    if (rem < 8) {                  // uniform masked tail
#pragma unroll
                        for (int k = 0; k < 8; ++k)
                            if (k >= rem) {
                                su[k] = 0u;
                                c[k] = make_float4(0.f, 0.f, 0.f, 0.f);
                            }
                    }
                    unsigned u[8];
#pragma unroll
                    for (int k = 0; k < 8; ++k)
                        u[k] = Au[(size_t)su[k] * 64 + lane];
#pragma unroll
                    for (int k = 0; k < 8; ++k) {
                        float lo = __uint_as_float(u[k] << 16);
                        float hi = __uint_as_float(u[k] & 0xffff0000u);
                        a0l += c[k].x * lo; a0h += c[k].x * hi;
                        a1l += c[k].y * lo; a1h += c[k].y * hi;
                        a2l += c[k].z * lo; a2h += c[k].z * hi;
                        a3l += c[k].w * lo; a3h += c[k].w * hi;
                    }
                }
            }
            // stage row into LDS: [hbf(256B) | S0 | S1 | S2 | S3], swizzled
            char* rp = (char*)S + row * 1280;
            int swz = (row & 7) << 4;
            *(unsigned int*)(rp + ((lane * 4) ^ swz)) = hb;
            *(unsigned int*)(rp + ((256 + lane * 4) ^ swz)) =
                (unsigned int)f2bf(a0l) | ((unsigned int)f2bf(a0h) << 16);
            *(unsigned int*)(rp + ((512 + lane * 4) ^ swz)) =
                (unsigned int)f2bf(a1l) | ((unsigned int)f2bf(a1h) << 16);
            *(unsigned int*)(rp + ((768 + lane * 4) ^ swz)) =
                (unsigned int)f2bf(a2l) | ((unsigned int)f2bf(a2h) << 16);
            *(unsigned int*)(rp + ((1024 + lane * 4) ^ swz)) =
                (unsigned int)f2bf(a3l) | ((unsigned int)f2bf(a3h) << 16);
        }
        __syncthreads();

        // Phase 2: rows 0..31, wave wv covers cols [wv*16, wv*16+16)
        f32x4 acc0 = (f32x4)0.f, acc1 = (f32x4)0.f;
#pragma unroll
        for (int ks = 0; ks < 20; ++ks) {
            int off = (ks * 64 + quad * 16) ^ swz2;
            bf16x8 a0 = *(const bf16x8*)(s0p + off);
            bf16x8 a1 = *(const bf16x8*)(s1p + off);
            bf16x8 b  = *(const bf16x8*)(bwp + (size_t)ks * 4096);
            acc0 = __builtin_amdgcn_mfma_f32_16x16x32_bf16(a0, b, acc0, 0, 0, 0);
            acc1 = __builtin_amdgcn_mfma_f32_16x16x32_bf16(a1, b, acc1, 0, 0, 0);
        }

        // C/D layout: col = lane&15, row = quad*4 + reg
        int col = (wv << 4) + n16;
        float bv = bias[col];
#pragma unroll
        for (int rg = 0; rg < 4; ++rg) {
            int r0 = nbase + quad * 4 + rg;
            if (r0 < N_NODES)
                out[(size_t)r0 * H_DIM + col] = fmaxf(acc0[rg] + bv, 0.f);
            int r1 = nbase + 16 + quad * 4 + rg;
            if (r1 < N_NODES)
                out[(size_t)r1 * H_DIM + col] = fmaxf(acc1[rg] + bv, 0.f);
        }
        __syncthreads();                    // LDS reads done before next tile
    }
}

extern "C" void kernel_launch(void* const* d_in, const int* in_sizes, int n_in,
                              void* d_out, int out_size, void* d_ws, size_t ws_size,
                              hipStream_t stream) {
    const float* h       = (const float*)d_in[0];
    const float* norm    = (const float*)d_in[1];
    const float* basis_w = (const float*)d_in[2];
    const float* w_comp  = (const float*)d_in[3];
    const float* loop_w  = (const float*)d_in[4];
    const float* bias    = (const float*)d_in[5];
    const int*   src     = (const int*)d_in[6];
    const int*   dst     = (const int*)d_in[7];
    const int*   etype   = (const int*)d_in[8];
    float* out = (float*)d_out;

    // ws layout (bytes):
    char* base = (char*)d_ws;
    unsigned short* wt3       = (unsigned short*)(base + 0);          //    163,840
    unsigned short* A         = (unsigned short*)(base + 163840);     // 12,800,000
    int*            offs      = (int*)(base + 12963840);              //    200,004
    uint2*          pkd       = (uint2*)(base + 13163848);            //  6,400,000
    uint2*          bucketed  = (uint2*)(base + 19563848);            //  6,400,000
    float4*         sorted_cf = (float4*)(base + 25963856);           // 12,800,256
    unsigned*       sorted_src= (unsigned*)(base + 38764112);         //  3,200,064
    int*            gcnt      = (int*)(base + 41964176);              //    313,600
    int*            blkbase   = (int*)(base + 42277776);              //    313,600
    int*            btot      = (int*)(base + 42591376);              //        784
    // total ~42.6 MB

    edge_pack<<<EP_BLOCKS, 1024, 0, stream>>>(src, dst, etype, norm,
                                              pkd, gcnt,
                                              sorted_src, sorted_cf);
    bucket_scan_a<<<N_RANGES, 512, 0, stream>>>(gcnt, blkbase, btot);
    stage2<<<EP_BLOCKS + CAST_BLOCKS + 5, 512, 0, stream>>>(
        h, basis_w, loop_w, pkd, blkbase, btot, A, wt3, bucketed);
    bucket_sort<<<N_RANGES, 1024, 0, stream>>>(btot, bucketed, w_comp,
                                               sorted_src, sorted_cf, offs);
    agg_gemm<<<AGG_GRID, 512, 0, stream>>>(offs, sorted_src, sorted_cf,
                                           A, wt3, bias, out);
}

// Round 13
// 165.608 us; speedup vs baseline: 1.0810x; 1.0810x over previous
//
#include <hip/hip_runtime.h>
#include <stdint.h>

#define N_NODES 50000
#define N_EDGES 800000
#define H_DIM 128
#define N_REL 40
#define N_BASES 4
#define N_RANGES 196         // node ranges of 256 (dst >> 8)
#define EP_BLOCKS 400        // edge chunks of 2000
#define EDGES_PER_BLK 2000
#define STAGE_CAP 5120       // LDS staging capacity for bucket_sort
#define CAST_BLOCKS 1563     // ceil(800000/512)

typedef __attribute__((ext_vector_type(8))) short bf16x8;
typedef __attribute__((ext_vector_type(4))) float f32x4;

// round-to-nearest-even f32 -> bf16 bits
__device__ __forceinline__ unsigned short f2bf(float f) {
    unsigned int u = __float_as_uint(f);
    unsigned int r = u + 0x7fffu + ((u >> 16) & 1u);
    return (unsigned short)(r >> 16);
}

// ---------------------------------------------------------------------------
// K0: edge_pack (400 blocks x 1024, 2000 edges each — 2 iterations/block).
// Pack edges + per-(chunk,bucket) LDS histogram -> gcnt[chunk][range].
// Block 0 zeroes the 16-entry over-read pad. LDS atomics only.
// pkd[e] = { src | etype<<20 , dst | nbf<<17 }  (nbf = bf16 of norm >= 0)
__global__ __launch_bounds__(1024) void edge_pack(
        const int* __restrict__ src, const int* __restrict__ dst,
        const int* __restrict__ etype, const float* __restrict__ norm,
        uint2* __restrict__ pkd, int* __restrict__ gcnt,
        unsigned* __restrict__ sorted_src, float4* __restrict__ sorted_cf) {
    __shared__ int lhist[N_RANGES];
    int blk = blockIdx.x;                   // 0..399
    int t = threadIdx.x;
    if (t < N_RANGES) lhist[t] = 0;
    if (blk == 0 && t >= 1008) {            // zero over-read pad
        int k = t - 1008;                   // 0..15
        sorted_src[N_EDGES + k] = 0u;
        sorted_cf[N_EDGES + k] = make_float4(0.f, 0.f, 0.f, 0.f);
    }
    __syncthreads();
    int e0 = blk * EDGES_PER_BLK;
    for (int i = t; i < EDGES_PER_BLK; i += 1024) {
        int e = e0 + i;
        int d = dst[e];
        unsigned int nbf = f2bf(norm[e]);   // <= 0x7FFF (norm >= 0)
        pkd[e] = make_uint2((unsigned)src[e] | ((unsigned)etype[e] << 20),
                            (unsigned)d | (nbf << 17));
        atomicAdd(&lhist[d >> 8], 1);
    }
    __syncthreads();
    if (t < N_RANGES) gcnt[blk * N_RANGES + t] = lhist[t];
}

// ---------------------------------------------------------------------------
// K1: bucket_scan_a (196 blocks x 512). Block r scans its bucket's 400
// chunk-counts -> RELATIVE blkbase[chunk][range] + bucket total btot[r].
__global__ __launch_bounds__(512) void bucket_scan_a(
        const int* __restrict__ gcnt, int* __restrict__ blkbase,
        int* __restrict__ btot) {
    __shared__ int wsum[8];
    int r = blockIdx.x;
    int t = threadIdx.x, lane = t & 63, w = t >> 6;
    int x = (t < EP_BLOCKS) ? gcnt[t * N_RANGES + r] : 0;
    int v = x;
#pragma unroll
    for (int d = 1; d < 64; d <<= 1) {
        int y = __shfl_up(v, d);
        if (lane >= d) v += y;
    }
    if (lane == 63) wsum[w] = v;
    __syncthreads();
    int wpre = 0;
#pragma unroll
    for (int ww = 0; ww < 7; ++ww)
        if (w > ww) wpre += wsum[ww];
    if (t < EP_BLOCKS) blkbase[t * N_RANGES + r] = wpre + v - x;
    if (t == 511) btot[r] = wpre + v;
}

// ---------------------------------------------------------------------------
// K2: stage2 (fused for overlap — scatter's low machine fill is covered by
// independent streaming blocks in the SAME dispatch):
//   blocks 0..399      : binscatter chunk b -> bucket-grouped order. Bases:
//                        196-wide shuffle scan of btot -> bstart; cursor =
//                        bstart + blkbase[b][range] (precomputed, coalesced).
//   blocks 400..1962   : cast h -> A bf16 (stride 128).
//   blocks 1963..1967  : repack basis_w/loop_w into frag-major wt3.
__global__ __launch_bounds__(512) void stage2(
        const float* __restrict__ h,
        const float* __restrict__ basis_w, const float* __restrict__ loop_w,
        const uint2* __restrict__ pkd, const int* __restrict__ blkbase,
        const int* __restrict__ btot,
        unsigned short* __restrict__ A, unsigned short* __restrict__ wt3,
        uint2* __restrict__ bucketed) {
    __shared__ int lcur[N_RANGES];
    __shared__ int wsum[8];
    int bid = blockIdx.x;
    int t = threadIdx.x;
    if (bid < EP_BLOCKS) {
        int lane = t & 63, w = t >> 6;
        int b = bid;
        int x = (t < N_RANGES) ? btot[t] : 0;
        int v = x;
#pragma unroll
        for (int d = 1; d < 64; d <<= 1) {
            int y = __shfl_up(v, d);
            if (lane >= d) v += y;
        }
        if (lane == 63) wsum[w] = v;
        __syncthreads();
        int wpre = 0;
#pragma unroll
        for (int ww = 0; ww < 7; ++ww)
            if (w > ww) wpre += wsum[ww];
        if (t < N_RANGES)
            lcur[t] = (wpre + v - x) + blkbase[b * N_RANGES + t];
        __syncthreads();
        int e0 = b * EDGES_PER_BLK;
        for (int i = t; i < EDGES_PER_BLK; i += 512) {
            uint2 p = pkd[e0 + i];
            int r = (p.y & 0x1FFFF) >> 8;
            int pos = atomicAdd(&lcur[r], 1);
            bucketed[pos] = p;
        }
    } else if (bid < EP_BLOCKS + CAST_BLOCKS) {
        int g = (bid - EP_BLOCKS) * 512 + t;    // [0, 800256)
        if (g < 800000) {
            int row = g >> 4;
            int cb = (g & 15) * 8;
            const float* p = h + (size_t)row * 128 + cb;
            float4 a0 = ((const float4*)p)[0];
            float4 a1 = ((const float4*)p)[1];
            bf16x8 o;
            o[0] = (short)f2bf(a0.x); o[1] = (short)f2bf(a0.y);
            o[2] = (short)f2bf(a0.z); o[3] = (short)f2bf(a0.w);
            o[4] = (short)f2bf(a1.x); o[5] = (short)f2bf(a1.y);
            o[6] = (short)f2bf(a1.z); o[7] = (short)f2bf(a1.w);
            *(bf16x8*)(A + (size_t)row * H_DIM + cb) = o;
        }
    } else {
        int mat = bid - EP_BLOCKS - CAST_BLOCKS;    // 0..3 basis, 4 loop
        const float* srcm = (mat < 4) ? (basis_w + mat * 16384) : loop_w;
        int koff = (mat < 4) ? (128 + mat * 128) : 0;
#pragma unroll
        for (int i = 0; i < 8; ++i) {
            int f = t + i * 512;                // [0,4096) float4 index
            int k = f >> 5;
            int j4 = (f & 31) * 4;
            float4 v = ((const float4*)srcm)[f];
            int kg = koff + k;
            int ks = kg >> 5;
            int quad = (kg >> 3) & 3;
            int jj = kg & 7;
            float vv[4] = {v.x, v.y, v.z, v.w};
#pragma unroll
            for (int d = 0; d < 4; ++d) {
                int j = j4 + d;
                int cg = j >> 4;
                int n16 = j & 15;
                wt3[(size_t)((ks * 8 + cg) * 64 + quad * 16 + n16) * 8 + jj] =
                    f2bf(vv[d]);
            }
        }
    }
}

// ---------------------------------------------------------------------------
// K3: bucket_sort (196 blocks x 1024 — round-10 version; the 4-way node
// split of round 11 regressed via 4x redundant histogram reads). One block
// per bucket; begin from a 196-wide scan of btot (precomputed).
// Pass 1: LDS per-dst histogram -> scan -> per-dst offsets (offs coalesced).
// Pass 2: place edges into LDS stage by exact sorted position, stream out
// coalesced as sorted_src (u32) + sorted_cf (float4 = w_comp[etype]*norm).
__global__ __launch_bounds__(1024) void bucket_sort(
        const int* __restrict__ btot, const uint2* __restrict__ bucketed,
        const float* __restrict__ w_comp,
        unsigned* __restrict__ sorted_src, float4* __restrict__ sorted_cf,
        int* __restrict__ offs) {
    __shared__ int hist[256];
    __shared__ int cur[256];
    __shared__ int wsum[16];
    __shared__ int sbeg;
    __shared__ uint2 stage[STAGE_CAP];
    int r = blockIdx.x;
    int t = threadIdx.x, lane = t & 63, w = t >> 6;
    int x = (t < N_RANGES) ? btot[t] : 0;
    int v = x;
#pragma unroll
    for (int d = 1; d < 64; d <<= 1) {
        int y = __shfl_up(v, d);
        if (lane >= d) v += y;
    }
    if (lane == 63) wsum[w] = v;
    if (t < 256) hist[t] = 0;
    __syncthreads();
    int wpre = 0;
#pragma unroll
    for (int ww = 0; ww < 15; ++ww)
        if (w > ww) wpre += wsum[ww];
    if (t == r) sbeg = wpre + v - x;
    __syncthreads();
    int begin = sbeg;
    int n = btot[r];
    int end = begin + n;
    for (int i = begin + t; i < end; i += 1024)
        atomicAdd(&hist[bucketed[i].y & 255], 1);
    __syncthreads();
    int x2 = (t < 256) ? hist[t] : 0;
    int v2 = x2;
#pragma unroll
    for (int d = 1; d < 64; d <<= 1) {
        int y = __shfl_up(v2, d);
        if (lane >= d) v2 += y;
    }
    if (lane == 63) wsum[w] = v2;
    __syncthreads();
    if (t < 256) {
        int wpre2 = 0;
#pragma unroll
        for (int ww = 0; ww < 3; ++ww)      // only waves 0..3 hold hist
            if (w > ww) wpre2 += wsum[ww];
        int excl_rel = wpre2 + v2 - x2;     // position within the region
        int node = r * 256 + t;
        if (node < N_NODES) offs[node] = begin + excl_rel;
        cur[t] = excl_rel;
    }
    if (r == N_RANGES - 1 && t == 0) offs[N_NODES] = N_EDGES;
    __syncthreads();
    if (n <= STAGE_CAP) {
        for (int i = begin + t; i < end; i += 1024) {
            uint2 p = bucketed[i];
            int pos = atomicAdd(&cur[p.y & 255], 1);
            stage[pos] = make_uint2(p.x, (p.y >> 17) << 16);
        }
        __syncthreads();
        for (int i = t; i < n; i += 1024) {
            uint2 p = stage[i];
            float nm = __uint_as_float(p.y);
            float4 wc = ((const float4*)w_comp)[p.x >> 20];
            sorted_src[begin + i] = p.x & 0xFFFFF;
            sorted_cf[begin + i] =
                make_float4(wc.x * nm, wc.y * nm, wc.z * nm, wc.w * nm);
        }
    } else {                                    // pathological fallback
        for (int i = begin + t; i < end; i += 1024) {
            uint2 p = bucketed[i];
            int pos = atomicAdd(&cur[p.y & 255], 1);
            float nm = __uint_as_float((p.y >> 17) << 16);
            float4 wc = ((const float4*)w_comp)[p.x >> 20];
            sorted_src[begin + pos] = p.x & 0xFFFFF;
            sorted_cf[begin + pos] =
                make_float4(wc.x * nm, wc.y * nm, wc.z * nm, wc.w * nm);
        }
    }
}

// ---------------------------------------------------------------------------
// K4 (fused aggregate + GEMM) — the verified single-tile kernel (static grid
// 1563, VGPR=20, ~48us). Multi-tile loops (persistent r3/r4, static 2-tile
// r12) ALL spill ~100MB scratch and regress; gather ping-pong (r8) null;
// packed FMA (r3) spills. This structure is the local optimum.
// 512 threads / 8 waves, 32-node tile.
// Phase 1: wave w aggregates nodes [32*blk + 4w, +4); edge metadata from
// sorted_src/sorted_cf (wave-uniform -> s_load batches of 8); gathers are
// 256B bf16 rows, 8 outstanding; MASKED full batch for the remainder.
// Node's 512-wide f32 S -> bf16 -> LDS tile [32][640] (with own hbf row),
// rows XOR-swizzled (byte ^= (row&7)<<4) for bank-uniform ds_read_b128.
// Phase 2: 32x128x640 bf16 MFMA from LDS; wave = 16 cols; bias+relu.
__global__ __launch_bounds__(512, 8) void agg_gemm(
        const int* __restrict__ offs, const unsigned* __restrict__ ssrc,
        const float4* __restrict__ scf,
        const unsigned short* __restrict__ Ab,
        const unsigned short* __restrict__ wt3,
        const float* __restrict__ bias, float* __restrict__ out) {
    __shared__ __align__(16) unsigned short S[32 * 640];   // 40 KB
    int wv = threadIdx.x >> 6;
    int lane = threadIdx.x & 63;
    int nbase = blockIdx.x * 32;
    const unsigned int* Au = (const unsigned int*)Ab;

#pragma unroll
    for (int q = 0; q < 4; ++q) {
        int row = (wv << 2) + q;
        int v = __builtin_amdgcn_readfirstlane(nbase + row);
        float a0l = 0.f, a0h = 0.f, a1l = 0.f, a1h = 0.f;
        float a2l = 0.f, a2h = 0.f, a3l = 0.f, a3h = 0.f;
        unsigned int hb = 0u;
        if (v < N_NODES) {
            hb = Au[(size_t)v * 64 + lane];     // own hbf row (cols 2l,2l+1)
            int begin = __builtin_amdgcn_readfirstlane(offs[v]);
            int end   = __builtin_amdgcn_readfirstlane(offs[v + 1]);
            for (int j = begin; j < end; j += 8) {
                int rem = end - j;              // uniform
                unsigned su[8];
                float4 c[8];
#pragma unroll
                for (int k = 0; k < 8; ++k) su[k] = ssrc[j + k];
#pragma unroll
                for (int k = 0; k < 8; ++k) c[k] = scf[j + k];
                if (rem < 8) {                  // uniform masked tail batch
#pragma unroll
                    for (int k = 0; k < 8; ++k)
                        if (k >= rem) {
                            su[k] = 0u;
                            c[k] = make_float4(0.f, 0.f, 0.f, 0.f);
                        }
                }
                unsigned u[8];
#pragma unroll
                for (int k = 0; k < 8; ++k)
                    u[k] = Au[(size_t)su[k] * 64 + lane];
#pragma unroll
                for (int k = 0; k < 8; ++k) {
                    float lo = __uint_as_float(u[k] << 16);
                    float hi = __uint_as_float(u[k] & 0xffff0000u);
                    a0l += c[k].x * lo; a0h += c[k].x * hi;
                    a1l += c[k].y * lo; a1h += c[k].y * hi;
                    a2l += c[k].z * lo; a2h += c[k].z * hi;
                    a3l += c[k].w * lo; a3h += c[k].w * hi;
                }
            }
        }
        // stage row into LDS: [hbf(256B) | S0 | S1 | S2 | S3], swizzled
        char* rp = (char*)S + row * 1280;
        int swz = (row & 7) << 4;
        *(unsigned int*)(rp + ((lane * 4) ^ swz)) = hb;
        *(unsigned int*)(rp + ((256 + lane * 4) ^ swz)) =
            (unsigned int)f2bf(a0l) | ((unsigned int)f2bf(a0h) << 16);
        *(unsigned int*)(rp + ((512 + lane * 4) ^ swz)) =
            (unsigned int)f2bf(a1l) | ((unsigned int)f2bf(a1h) << 16);
        *(unsigned int*)(rp + ((768 + lane * 4) ^ swz)) =
            (unsigned int)f2bf(a2l) | ((unsigned int)f2bf(a2h) << 16);
        *(unsigned int*)(rp + ((1024 + lane * 4) ^ swz)) =
            (unsigned int)f2bf(a3l) | ((unsigned int)f2bf(a3h) << 16);
    }
    __syncthreads();

    // Phase 2: rows 0..31 of LDS tile, wave wv covers cols [wv*16, wv*16+16)
    int n16 = lane & 15;
    int quad = lane >> 4;
    f32x4 acc0 = (f32x4)0.f, acc1 = (f32x4)0.f;

    const char* s0p = (const char*)S + n16 * 1280;
    const char* s1p = s0p + 16 * 1280;
    int swz2 = (n16 & 7) << 4;
    const unsigned short* bwp = wt3 + (size_t)wv * 512 + (size_t)lane * 8;

#pragma unroll
    for (int ks = 0; ks < 20; ++ks) {
        int off = (ks * 64 + quad * 16) ^ swz2;
        bf16x8 a0 = *(const bf16x8*)(s0p + off);
        bf16x8 a1 = *(const bf16x8*)(s1p + off);
        bf16x8 b  = *(const bf16x8*)(bwp + (size_t)ks * 4096);
        acc0 = __builtin_amdgcn_mfma_f32_16x16x32_bf16(a0, b, acc0, 0, 0, 0);
        acc1 = __builtin_amdgcn_mfma_f32_16x16x32_bf16(a1, b, acc1, 0, 0, 0);
    }

    // C/D layout: col = lane&15, row = quad*4 + reg
    int col = (wv << 4) + n16;
    float bv = bias[col];
#pragma unroll
    for (int rg = 0; rg < 4; ++rg) {
        int r0 = nbase + quad * 4 + rg;
        if (r0 < N_NODES)
            out[(size_t)r0 * H_DIM + col] = fmaxf(acc0[rg] + bv, 0.f);
        int r1 = nbase + 16 + quad * 4 + rg;
        if (r1 < N_NODES)
            out[(size_t)r1 * H_DIM + col] = fmaxf(acc1[rg] + bv, 0.f);
    }
}

extern "C" void kernel_launch(void* const* d_in, const int* in_sizes, int n_in,
                              void* d_out, int out_size, void* d_ws, size_t ws_size,
                              hipStream_t stream) {
    const float* h       = (const float*)d_in[0];
    const float* norm    = (const float*)d_in[1];
    const float* basis_w = (const float*)d_in[2];
    const float* w_comp  = (const float*)d_in[3];
    const float* loop_w  = (const float*)d_in[4];
    const float* bias    = (const float*)d_in[5];
    const int*   src     = (const int*)d_in[6];
    const int*   dst     = (const int*)d_in[7];
    const int*   etype   = (const int*)d_in[8];
    float* out = (float*)d_out;

    // ws layout (bytes):
    char* base = (char*)d_ws;
    unsigned short* wt3       = (unsigned short*)(base + 0);          //    163,840
    unsigned short* A         = (unsigned short*)(base + 163840);     // 12,800,000
    int*            offs      = (int*)(base + 12963840);              //    200,004
    uint2*          pkd       = (uint2*)(base + 13163848);            //  6,400,000
    uint2*          bucketed  = (uint2*)(base + 19563848);            //  6,400,000
    float4*         sorted_cf = (float4*)(base + 25963856);           // 12,800,256
    unsigned*       sorted_src= (unsigned*)(base + 38764112);         //  3,200,064
    int*            gcnt      = (int*)(base + 41964176);              //    313,600
    int*            blkbase   = (int*)(base + 42277776);              //    313,600
    int*            btot      = (int*)(base + 42591376);              //        784
    // total ~42.6 MB

    edge_pack<<<EP_BLOCKS, 1024, 0, stream>>>(src, dst, etype, norm,
                                              pkd, gcnt,
                                              sorted_src, sorted_cf);
    bucket_scan_a<<<N_RANGES, 512, 0, stream>>>(gcnt, blkbase, btot);
    stage2<<<EP_BLOCKS + CAST_BLOCKS + 5, 512, 0, stream>>>(
        h, basis_w, loop_w, pkd, blkbase, btot, A, wt3, bucketed);
    bucket_sort<<<N_RANGES, 1024, 0, stream>>>(btot, bucketed, w_comp,
                                               sorted_src, sorted_cf, offs);
    agg_gemm<<<1563, 512, 0, stream>>>(offs, sorted_src, sorted_cf,
                                       A, wt3, bias, out);
}